// Round 5
// baseline (173.156 us; speedup 1.0000x reference)
//
#include <hip/hip_runtime.h>

typedef unsigned short u16;
typedef __attribute__((ext_vector_type(8))) short frag8;   // 8 bf16 (4 VGPRs)
typedef __attribute__((ext_vector_type(4))) float f32x4;   // MFMA accumulator

__device__ __forceinline__ u16 f2bf(float f) {
  unsigned u; __builtin_memcpy(&u, &f, 4);
  u = (u + 0x7FFFu + ((u >> 16) & 1u)) >> 16;   // RNE (== v_cvt_pk_bf16_f32)
  return (u16)u;
}

// ---------------------------------------------------------------------------
// Round-11: max out memory-level parallelism in the pixel path.
// Evidence: R4 (prep-kernel, zero-barrier, wave=tile) landed at ~55 us -- only
// ~8 us better; all five structures sit at 55-66 us with HBM at ~1.35 TB/s.
// Little's law: 6.3 TB/s needs ~6 KB in flight per CU; VGPR_Count=88 proves
// the compiler batches the 48 per-lane pixel loads (~1 KB in flight per CU
// -> predicted 1.4 TB/s == measured 1.35). The kernel is latency-bound on
// outstanding loads, not on structure.
// Fix: straight-line load ALL 48 float4s of the tile into float4 P[48]
// (static indexing only), THEN compute. 192 VGPRs of loads in flight/wave;
// 8 waves/CU x 48 x 16B = 6 KB/CU outstanding = BW-saturating.
// __launch_bounds__(64,2) caps at 256 VGPR, preserving 8 blocks/CU.
// Arithmetic order identical to R4 -> absmax expected unchanged (0.015625).
// ---------------------------------------------------------------------------

#define FEATW_OFF 0       // 2048 B  [64 p][16 coeff] bf16
#define HW_OFF    2048    // 4096 B  [64 p][32 n] bf16, XOR-swizzled
#define SMEM_BYTES 6144

__global__ __launch_bounds__(256)
void prep_weights(const float* __restrict__ W1, const float* __restrict__ W2,
                  u16* __restrict__ wf) {
  const int g    = blockIdx.x * 256 + threadIdx.x;   // 0..3071
  const int quad = (g >> 4) & 3;
  const int l16  = g & 15;
  frag8 f;
  if (g < 1024) {
    // w1f[nt][lane]: A-frag of W1^T, f[j] = W1[k=quad*8+j][nt*16+l16], k>=16 -> 0
    const int nt = g >> 6;
    #pragma unroll
    for (int j = 0; j < 8; ++j) {
      const int k = quad * 8 + j;
      f[j] = (k < 16) ? (short)f2bf(W1[k * 256 + nt * 16 + l16]) : (short)0;
    }
    *(frag8*)(wf + (size_t)g * 8) = f;
  } else {
    // w2f[kc*4+et][lane]: B-frag, f[j] = W2[kc*32+quad*8+j][et*16+l16]
    const int idx = g - 1024;                        // 0..2047
    const int kc  = idx >> 8;
    const int et  = (idx >> 6) & 3;
    #pragma unroll
    for (int j = 0; j < 8; ++j)
      f[j] = (short)f2bf(W2[(kc * 32 + quad * 8 + j) * 64 + et * 16 + l16]);
    *(frag8*)(wf + 8192 + (size_t)idx * 8) = f;
  }
}

__global__ __launch_bounds__(64, 2)   // 1 wave/block; <=256 VGPR; 8 blocks/CU
void dct_mlp_fused(const float* __restrict__ x,
                   const u16* __restrict__ wf,
                   const float* __restrict__ b1,
                   const float* __restrict__ b2,
                   float* __restrict__ out) {
  __shared__ __align__(16) char smem[SMEM_BYTES];

  const int lane = threadIdx.x;     // lane == patch index within the tile
  const int quad = lane >> 4;
  const int l16  = lane & 15;

  const int tile = blockIdx.x;      // 0..2047
  const int gy   = tile & 63;
  const int b    = tile >> 6;

  // ======== Pixel loads: ALL 48 dwordx4 issued up-front (6 KB/CU MLP) ======
  float4 P[48];   // [ch][row][half] = ch*16 + i*2 + q   (static indices only)
  const float* px = x + (size_t)(b * 3) * 262144 + (size_t)gy * 4096 + lane * 8;
  #pragma unroll
  for (int ch = 0; ch < 3; ++ch)
    #pragma unroll
    for (int i = 0; i < 8; ++i) {
      const float* row = px + ch * 262144 + i * 512;
      P[ch * 16 + i * 2]     = ((const float4*)row)[0];
      P[ch * 16 + i * 2 + 1] = ((const float4*)row)[1];
    }

  // ======== DCT: register-only, lane = patch ========
  const float D4[4][8] = {
    { 0.35355339f, 0.35355339f, 0.35355339f, 0.35355339f,
      0.35355339f, 0.35355339f, 0.35355339f, 0.35355339f},
    { 0.49039264f, 0.41573481f, 0.27778512f, 0.09754516f,
     -0.09754516f,-0.27778512f,-0.41573481f,-0.49039264f},
    { 0.46193977f, 0.19134172f,-0.19134172f,-0.46193977f,
     -0.46193977f,-0.19134172f, 0.19134172f, 0.46193977f},
    { 0.41573481f,-0.09754516f,-0.49039264f,-0.27778512f,
      0.27778512f, 0.49039264f, 0.09754516f,-0.41573481f}
  };

  float tmp[4][8];
  #pragma unroll
  for (int kr = 0; kr < 4; ++kr)
    #pragma unroll
    for (int c = 0; c < 8; ++c) tmp[kr][c] = 0.f;

  #pragma unroll
  for (int i = 0; i < 8; ++i) {
    float4 r0  = P[i * 2],      r1  = P[i * 2 + 1];
    float4 g0  = P[16 + i * 2], g1v = P[16 + i * 2 + 1];
    float4 c0  = P[32 + i * 2], c1  = P[32 + i * 2 + 1];
    float gr[8];
    gr[0] = 0.299f * r0.x + 0.587f * g0.x + 0.114f * c0.x;
    gr[1] = 0.299f * r0.y + 0.587f * g0.y + 0.114f * c0.y;
    gr[2] = 0.299f * r0.z + 0.587f * g0.z + 0.114f * c0.z;
    gr[3] = 0.299f * r0.w + 0.587f * g0.w + 0.114f * c0.w;
    gr[4] = 0.299f * r1.x + 0.587f * g1v.x + 0.114f * c1.x;
    gr[5] = 0.299f * r1.y + 0.587f * g1v.y + 0.114f * c1.y;
    gr[6] = 0.299f * r1.z + 0.587f * g1v.z + 0.114f * c1.z;
    gr[7] = 0.299f * r1.w + 0.587f * g1v.w + 0.114f * c1.w;
    #pragma unroll
    for (int kr = 0; kr < 4; ++kr)
      #pragma unroll
      for (int c = 0; c < 8; ++c)
        tmp[kr][c] = fmaf(D4[kr][i], gr[c], tmp[kr][c]);
  }

  // col pass + write feats (16 coeffs) to per-block LDS scratch
  char* featWw = smem + FEATW_OFF;
  #pragma unroll
  for (int kr = 0; kr < 4; ++kr) {
    float cc[4] = {0.f, 0.f, 0.f, 0.f};
    #pragma unroll
    for (int l = 0; l < 4; ++l)
      #pragma unroll
      for (int j = 0; j < 8; ++j)
        cc[l] = fmaf(tmp[kr][j], D4[l][j], cc[l]);
    ushort4 fv;
    fv.x = f2bf(cc[0]); fv.y = f2bf(cc[1]); fv.z = f2bf(cc[2]); fv.w = f2bf(cc[3]);
    *(ushort4*)(featWw + lane * 32 + kr * 8) = fv;
  }

  // feats B-fragments (kc-invariant): B[k=quad*8+j][p=l16], k>=16 zero.
  // Wave-local LDS round-trip; compiler-inserted lgkmcnt, no barrier needed.
  frag8 fB[4];
  #pragma unroll
  for (int pt = 0; pt < 4; ++pt) {
    frag8 z = {0,0,0,0,0,0,0,0};
    if (quad < 2)
      z = *(const frag8*)(featWw + (pt * 16 + l16) * 32 + quad * 16);
    fB[pt] = z;
  }

  float b2e[4];
  #pragma unroll
  for (int et = 0; et < 4; ++et) b2e[et] = b2[et * 16 + l16];

  f32x4 accs[4][4];
  #pragma unroll
  for (int pt = 0; pt < 4; ++pt)
    #pragma unroll
    for (int et = 0; et < 4; ++et) {
      f32x4 a = {b2e[et], b2e[et], b2e[et], b2e[et]};
      accs[pt][et] = a;
    }

  char* hWw = smem + HW_OFF;
  const unsigned hswz = (unsigned)((l16 & 3) << 4);   // p&3 == l16&3

  const u16* w1f = wf;          // frag8 per (nt, lane): nt*512 + lane*8 u16
  const u16* w2f = wf + 8192;   // frag8 per (kc*4+et, lane)

  #pragma unroll
  for (int kc = 0; kc < 8; ++kc) {
    // ---- weight fragments: one coalesced dwordx4 per frag, L2-hot ----
    frag8 a0 = *(const frag8*)(w1f + (size_t)(2 * kc) * 512 + lane * 8);
    frag8 a1 = *(const frag8*)(w1f + (size_t)(2 * kc + 1) * 512 + lane * 8);
    frag8 w2b[4];
    #pragma unroll
    for (int et = 0; et < 4; ++et)
      w2b[et] = *(const frag8*)(w2f + (size_t)(kc * 4 + et) * 512 + lane * 8);

    // ---- GEMM1: h chunk (32 hidden) = W1^T @ feats^T + b1, relu ----
    f32x4 g1[2][4];
    #pragma unroll
    for (int ntl = 0; ntl < 2; ++ntl) {
      float4 bb = *(const float4*)(b1 + kc * 32 + ntl * 16 + quad * 4);
      #pragma unroll
      for (int pt = 0; pt < 4; ++pt) {
        f32x4 ac = {bb.x, bb.y, bb.z, bb.w};
        g1[ntl][pt] = __builtin_amdgcn_mfma_f32_16x16x32_bf16(
            ntl ? a1 : a0, fB[pt], ac, 0, 0, 0);
      }
    }
    // relu + pack -> hW (swizzled)
    #pragma unroll
    for (int pt = 0; pt < 4; ++pt) {
      const unsigned rb = (unsigned)((pt * 16 + l16) * 64);
      #pragma unroll
      for (int ntl = 0; ntl < 2; ++ntl) {
        f32x4 v = g1[ntl][pt];
        float m0 = fmaxf(v[0], 0.f), m1 = fmaxf(v[1], 0.f);
        float m2 = fmaxf(v[2], 0.f), m3 = fmaxf(v[3], 0.f);
        unsigned d0, d1;
        asm("v_cvt_pk_bf16_f32 %0, %1, %2" : "=v"(d0) : "v"(m0), "v"(m1));
        asm("v_cvt_pk_bf16_f32 %0, %1, %2" : "=v"(d1) : "v"(m2), "v"(m3));
        uint2 dd; dd.x = d0; dd.y = d1;
        *(uint2*)(hWw + ((rb + ntl * 32 + quad * 8) ^ hswz)) = dd;
      }
    }
    // ---- GEMM2: emb += h_chunk @ W2[kc*32 .. kc*32+31][:] ----
    frag8 hA[4];
    #pragma unroll
    for (int pt = 0; pt < 4; ++pt) {
      const unsigned rb = (unsigned)((pt * 16 + l16) * 64);
      hA[pt] = *(const frag8*)(hWw + ((rb + quad * 16) ^ hswz));
    }
    #pragma unroll
    for (int pt = 0; pt < 4; ++pt)
      #pragma unroll
      for (int et = 0; et < 4; ++et)
        accs[pt][et] = __builtin_amdgcn_mfma_f32_16x16x32_bf16(
            hA[pt], w2b[et], accs[pt][et], 0, 0, 0);
  }

  // ======== Epilogue: direct store (lane regs j=0..3 are contiguous p) ======
  #pragma unroll
  for (int pt = 0; pt < 4; ++pt)
    #pragma unroll
    for (int et = 0; et < 4; ++et) {
      f32x4 v = accs[pt][et];
      float4 o; o.x = v[0]; o.y = v[1]; o.z = v[2]; o.w = v[3];
      float* dst = out + (((size_t)b * 64 + et * 16 + l16) * 64 + gy) * 64
                       + pt * 16 + quad * 4;
      *(float4*)dst = o;
    }
}

extern "C" void kernel_launch(void* const* d_in, const int* in_sizes, int n_in,
                              void* d_out, int out_size, void* d_ws, size_t ws_size,
                              hipStream_t stream) {
  const float* x  = (const float*)d_in[0];
  const float* W1 = (const float*)d_in[1];
  const float* b1 = (const float*)d_in[2];
  const float* W2 = (const float*)d_in[3];
  const float* b2 = (const float*)d_in[4];
  float* out = (float*)d_out;
  u16* wf = (u16*)d_ws;   // needs 48 KB of workspace

  prep_weights<<<dim3(12, 1, 1), dim3(256, 1, 1), 0, stream>>>(W1, W2, wf);
  dct_mlp_fused<<<dim3(2048, 1, 1), dim3(64, 1, 1), 0, stream>>>(x, wf, b1, b2, out);
}